// Round 1
// baseline (2531.976 us; speedup 1.0000x reference)
//
#include <hip/hip_runtime.h>

#define N_NODES 50000
#define N_EDGES 300000
#define DIM 256
#define HID 128
#define INP 64
#define BATCH 4096
#define SEQ 50

typedef float f32x4 __attribute__((ext_vector_type(4)));
typedef __bf16 bf16x8 __attribute__((ext_vector_type(8)));

__device__ __forceinline__ float sigmoidf_(float x) {
    return 1.0f / (1.0f + __expf(-x));
}
__device__ __forceinline__ float tanhf_(float x) {
    x = fmaxf(-20.0f, fminf(20.0f, x));
    float e = __expf(-2.0f * x);
    return (1.0f - e) / (1.0f + e);
}

// ---------------- GCN ----------------

__global__ void k_deg(const int* __restrict__ head, float* __restrict__ deg) {
    int e = blockIdx.x * 256 + threadIdx.x;
    if (e < N_EDGES) atomicAdd(&deg[head[e]], 1.0f);
}

// one wave (64 lanes) per edge; lane q handles dims [4q, 4q+4)
__global__ void k_scatter(const int* __restrict__ head, const int* __restrict__ tail,
                          const int* __restrict__ etype, const float* __restrict__ relw,
                          const float* __restrict__ src, float* __restrict__ dst) {
    int gid = blockIdx.x * 256 + threadIdx.x;
    int e = gid >> 6;
    int q = gid & 63;
    if (e >= N_EDGES) return;
    int h = head[e], t = tail[e], r = etype[e];
    f32x4 v = *(const f32x4*)(src + (size_t)t * DIM + q * 4);
    f32x4 w = *(const f32x4*)(relw + (size_t)r * DIM + q * 4);
    float* d = dst + (size_t)h * DIM + q * 4;
    atomicAdd(d + 0, v.x * w.x);
    atomicAdd(d + 1, v.y * w.y);
    atomicAdd(d + 2, v.z * w.z);
    atomicAdd(d + 3, v.w * w.w);
}

__global__ void k_div(float* __restrict__ buf, const float* __restrict__ deg) {
    int i = blockIdx.x * 256 + threadIdx.x;   // over N*DIM
    int n = i >> 8;
    buf[i] /= fmaxf(deg[n], 1.0f);
}

__global__ void k_struct(const int* __restrict__ nidx, const float* __restrict__ emb,
                         const float* __restrict__ out1, const float* __restrict__ out2raw,
                         const float* __restrict__ deg, float* __restrict__ structb) {
    int i = blockIdx.x * 256 + threadIdx.x;   // over BATCH*DIM
    int b = i >> 8, d = i & 255;
    int n = nidx[b];
    size_t o = (size_t)n * DIM + d;
    float o2 = out2raw[o] / fmaxf(deg[n], 1.0f);
    structb[i] = (emb[o] + out1[o] + o2) * (1.0f / 3.0f);
}

// ---------------- BiLSTM ----------------
// Pack W = [Wih | Whh] (bf16, K=192) into MFMA B-fragment order:
// frag index = ((w*8+nt)*6+kc), within-frag = lane*8+j
// value = W2[n][k], n = gate(nt)*128 + w*32 + jt(nt)*16 + (lane&15),
//                   k = kc*32 + (lane>>4)*8 + j
__global__ void k_w2frag(const float* __restrict__ Wih_f, const float* __restrict__ Whh_f,
                         const float* __restrict__ Wih_b, const float* __restrict__ Whh_b,
                         __bf16* __restrict__ w2) {
    int idx = blockIdx.x * 256 + threadIdx.x;   // 2 * 96 * 1024 = 196608
    int dir = idx / 98304;
    int rem = idx % 98304;
    int frag = rem >> 10;
    int within = rem & 1023;
    int lane = within >> 3, j = within & 7;
    int kc = frag % 6;
    int wnt = frag / 6;
    int nt = wnt & 7, w = wnt >> 3;
    int gate = nt >> 1, jt = nt & 1;
    int n = gate * 128 + w * 32 + jt * 16 + (lane & 15);
    int k = kc * 32 + (lane >> 4) * 8 + j;
    const float* Wih = dir ? Wih_b : Wih_f;
    const float* Whh = dir ? Whh_b : Whh_f;
    float v = (k < 64) ? Wih[n * 64 + k] : Whh[n * 128 + (k - 64)];
    w2[idx] = (__bf16)v;
}

// Block = 4 waves, 32 batch samples, one direction, all 50 steps.
// Wave w owns hidden units j in [w*32, w*32+32) for ALL four gates.
__launch_bounds__(256)
__global__ void k_lstm(const float* __restrict__ ts, const __bf16* __restrict__ w2frag,
                       const float* __restrict__ b_f, const float* __restrict__ b_b,
                       float* __restrict__ temporal) {
    int dir = blockIdx.y;
    int btile = blockIdx.x;    // 0..127
    int tid = threadIdx.x;
    int w = tid >> 6;
    int lane = tid & 63;
    int col = lane & 15, quad = lane >> 4;

    __shared__ __align__(16) __bf16 A[32][200];   // [m][k], K=192 padded to 200

    // zero h region (k = 64..191)
    for (int i = tid; i < 32 * 128; i += 256) {
        A[i >> 7][64 + (i & 127)] = (__bf16)0.0f;
    }

    const float* bias = dir ? b_b : b_f;
    float bv[8];
#pragma unroll
    for (int nt = 0; nt < 8; nt++) {
        int n = (nt >> 1) * 128 + w * 32 + (nt & 1) * 16 + col;
        bv[nt] = bias[n];
    }
    const __bf16* wbase = w2frag + (size_t)dir * 98304 + (size_t)w * 49152;

    f32x4 c_reg[4], hsum[4];
#pragma unroll
    for (int s = 0; s < 4; s++) {
        c_reg[s] = (f32x4){0.f, 0.f, 0.f, 0.f};
        hsum[s]  = (f32x4){0.f, 0.f, 0.f, 0.f};
    }
    __syncthreads();

    for (int t = 0; t < SEQ; t++) {
        int tt = dir ? (SEQ - 1 - t) : t;
        // stage x_t: 32 rows x 64 cols; thread -> row=tid>>3, cols [(tid&7)*8, +8)
        {
            int m = tid >> 3, c8 = (tid & 7) * 8;
            int b = btile * 32 + m;
            const float* xp = ts + ((size_t)b * SEQ + tt) * INP + c8;
            f32x4 x0 = *(const f32x4*)(xp);
            f32x4 x1 = *(const f32x4*)(xp + 4);
            bf16x8 xv;
            xv[0] = (__bf16)x0.x; xv[1] = (__bf16)x0.y;
            xv[2] = (__bf16)x0.z; xv[3] = (__bf16)x0.w;
            xv[4] = (__bf16)x1.x; xv[5] = (__bf16)x1.y;
            xv[6] = (__bf16)x1.z; xv[7] = (__bf16)x1.w;
            *(bf16x8*)&A[m][c8] = xv;
        }
        __syncthreads();

        f32x4 acc[16];
#pragma unroll
        for (int nt = 0; nt < 8; nt++) {
            f32x4 z = (f32x4){bv[nt], bv[nt], bv[nt], bv[nt]};
            acc[nt * 2] = z;
            acc[nt * 2 + 1] = z;
        }
#pragma unroll
        for (int kc = 0; kc < 6; kc++) {
            bf16x8 a0 = *(const bf16x8*)&A[col][kc * 32 + quad * 8];
            bf16x8 a1 = *(const bf16x8*)&A[16 + col][kc * 32 + quad * 8];
#pragma unroll
            for (int nt = 0; nt < 8; nt++) {
                bf16x8 bfrag = *(const bf16x8*)(wbase + ((nt * 6 + kc) << 10) + lane * 8);
                acc[nt * 2]     = __builtin_amdgcn_mfma_f32_16x16x32_bf16(a0, bfrag, acc[nt * 2], 0, 0, 0);
                acc[nt * 2 + 1] = __builtin_amdgcn_mfma_f32_16x16x32_bf16(a1, bfrag, acc[nt * 2 + 1], 0, 0, 0);
            }
        }
        __syncthreads();   // everyone's A reads done before h_t overwrite

        // cell update: lane owns (b,j) pairs; i/f/g/o in same lane, same reg idx
#pragma unroll
        for (int m = 0; m < 2; m++) {
#pragma unroll
            for (int jt = 0; jt < 2; jt++) {
                int s = m * 2 + jt;
#pragma unroll
                for (int r = 0; r < 4; r++) {
                    float iv = acc[(0 * 2 + jt) * 2 + m][r];
                    float fv = acc[(1 * 2 + jt) * 2 + m][r];
                    float gv = acc[(2 * 2 + jt) * 2 + m][r];
                    float ov = acc[(3 * 2 + jt) * 2 + m][r];
                    float c = sigmoidf_(fv) * c_reg[s][r] + sigmoidf_(iv) * tanhf_(gv);
                    float h = sigmoidf_(ov) * tanhf_(c);
                    c_reg[s][r] = c;
                    hsum[s][r] += h;
                    A[m * 16 + quad * 4 + r][64 + w * 32 + jt * 16 + col] = (__bf16)h;
                }
            }
        }
    }

    // temporal[b][dir*128 + j] = mean over t of h
#pragma unroll
    for (int m = 0; m < 2; m++) {
#pragma unroll
        for (int jt = 0; jt < 2; jt++) {
            int s = m * 2 + jt;
#pragma unroll
            for (int r = 0; r < 4; r++) {
                int b = btile * 32 + m * 16 + quad * 4 + r;
                int j = w * 32 + jt * 16 + col;
                temporal[(size_t)b * 256 + dir * 128 + j] = hsum[s][r] * (1.0f / SEQ);
            }
        }
    }
}

// ---------------- Head ----------------

__global__ void k_gate(const float* __restrict__ structb, const float* __restrict__ temporal,
                       const float* __restrict__ gate_W, const float* __restrict__ gate_b,
                       float* __restrict__ merged) {
    int bt = blockIdx.x;      // 256 blocks x 16 samples
    int n = threadIdx.x;      // output unit
    __shared__ __align__(16) float cat[16][512];
    for (int i = n; i < 16 * 512; i += 256) {
        int bb = i >> 9, k = i & 511;
        int b = bt * 16 + bb;
        cat[bb][k] = (k < 256) ? structb[(size_t)b * 256 + k]
                               : temporal[(size_t)b * 256 + (k - 256)];
    }
    __syncthreads();
    float acc[16];
#pragma unroll
    for (int bb = 0; bb < 16; bb++) acc[bb] = gate_b[n];
    const float* wrow = gate_W + (size_t)n * 512;
    for (int k4 = 0; k4 < 512; k4 += 4) {
        f32x4 wv = *(const f32x4*)(wrow + k4);
#pragma unroll
        for (int bb = 0; bb < 16; bb++) {
            f32x4 cv = *(const f32x4*)&cat[bb][k4];
            acc[bb] += cv.x * wv.x + cv.y * wv.y + cv.z * wv.z + cv.w * wv.w;
        }
    }
    int b0 = bt * 16;
#pragma unroll
    for (int bb = 0; bb < 16; bb++) {
        float g = sigmoidf_(acc[bb]);
        float s = structb[(size_t)(b0 + bb) * 256 + n];
        float tm = temporal[(size_t)(b0 + bb) * 256 + n];
        merged[(size_t)(b0 + bb) * 256 + n] = g * s + (1.0f - g) * tm;
    }
}

__global__ void k_risk1(const float* __restrict__ merged, const float* __restrict__ W1,
                        const float* __restrict__ b1, float* __restrict__ t1) {
    int bt = blockIdx.x;      // 256 blocks x 16 samples
    int n = threadIdx.x;
    __shared__ __align__(16) float mt[16][256];
    for (int i = n; i < 16 * 256; i += 256) {
        int bb = i >> 8, k = i & 255;
        mt[bb][k] = merged[(size_t)(bt * 16 + bb) * 256 + k];
    }
    __syncthreads();
    float acc[16];
#pragma unroll
    for (int bb = 0; bb < 16; bb++) acc[bb] = b1[n];
    const float* wrow = W1 + (size_t)n * 256;
    for (int k4 = 0; k4 < 256; k4 += 4) {
        f32x4 wv = *(const f32x4*)(wrow + k4);
#pragma unroll
        for (int bb = 0; bb < 16; bb++) {
            f32x4 cv = *(const f32x4*)&mt[bb][k4];
            acc[bb] += cv.x * wv.x + cv.y * wv.y + cv.z * wv.z + cv.w * wv.w;
        }
    }
#pragma unroll
    for (int bb = 0; bb < 16; bb++) {
        t1[(size_t)(bt * 16 + bb) * 256 + n] = tanhf_(acc[bb]);
    }
}

// risk.sum(-1) collapses: sum_n(t1@W2^T + b2) = t1 . colsum(W2) + sum(b2)
__global__ void k_w2sum(const float* __restrict__ W2, const float* __restrict__ b2,
                        float* __restrict__ w2s) {
    int k = threadIdx.x;
    float s = 0.0f;
    for (int n = 0; n < 256; n++) s += W2[(size_t)n * 256 + k];
    w2s[k] = s;
    __shared__ float red[256];
    red[k] = b2[k];
    __syncthreads();
    for (int st = 128; st > 0; st >>= 1) {
        if (k < st) red[k] += red[k + st];
        __syncthreads();
    }
    if (k == 0) w2s[256] = red[0];
}

__global__ void k_final(const float* __restrict__ t1, const float* __restrict__ w2s,
                        float* __restrict__ out) {
    int b = (blockIdx.x * 256 + threadIdx.x) >> 6;   // one wave per sample
    int lane = threadIdx.x & 63;
    const float* row = t1 + (size_t)b * 256;
    float s = 0.0f;
#pragma unroll
    for (int q = 0; q < 4; q++) s += row[lane + q * 64] * w2s[lane + q * 64];
#pragma unroll
    for (int off = 32; off > 0; off >>= 1) s += __shfl_down(s, off, 64);
    if (lane == 0) out[b] = sigmoidf_(s + w2s[256]);
}

// ---------------- launch ----------------

extern "C" void kernel_launch(void* const* d_in, const int* in_sizes, int n_in,
                              void* d_out, int out_size, void* d_ws, size_t ws_size,
                              hipStream_t stream) {
    const float* ts       = (const float*)d_in[0];
    const float* node_emb = (const float*)d_in[1];
    const float* rel_w    = (const float*)d_in[2];
    const float* gate_W   = (const float*)d_in[3];
    const float* gate_b   = (const float*)d_in[4];
    const float* risk_W1  = (const float*)d_in[5];
    const float* risk_b1  = (const float*)d_in[6];
    const float* risk_W2  = (const float*)d_in[7];
    const float* risk_b2  = (const float*)d_in[8];
    const float* Wih_f    = (const float*)d_in[9];
    const float* Whh_f    = (const float*)d_in[10];
    const float* b_f      = (const float*)d_in[11];
    const float* Wih_b    = (const float*)d_in[12];
    const float* Whh_b    = (const float*)d_in[13];
    const float* b_b      = (const float*)d_in[14];
    const int* edge_index = (const int*)d_in[15];
    const int* edge_type  = (const int*)d_in[16];
    const int* node_idx   = (const int*)d_in[17];
    const int* head = edge_index;
    const int* tail = edge_index + N_EDGES;
    float* out = (float*)d_out;

    char* ws = (char*)d_ws;
    const size_t o_deg      = 0;                           // 50000 f, pad
    const size_t o_out1     = 200704;                      // 51,200,000 B
    const size_t o_out2     = o_out1 + 51200000;           // 51,200,000 B
    const size_t o_zero_end = o_out2 + 51200000;
    const size_t o_temporal = o_zero_end;                  // 4 MB
    const size_t o_struct   = o_temporal + 4194304;
    const size_t o_merged   = o_struct + 4194304;
    const size_t o_t1       = o_merged + 4194304;
    const size_t o_w2s      = o_t1 + 4194304;
    const size_t o_w2frag   = o_w2s + 2048;

    float*  deg      = (float*)(ws + o_deg);
    float*  out1     = (float*)(ws + o_out1);
    float*  out2     = (float*)(ws + o_out2);
    float*  temporal = (float*)(ws + o_temporal);
    float*  structb  = (float*)(ws + o_struct);
    float*  merged   = (float*)(ws + o_merged);
    float*  t1       = (float*)(ws + o_t1);
    float*  w2s      = (float*)(ws + o_w2s);
    __bf16* w2frag   = (__bf16*)(ws + o_w2frag);

    hipMemsetAsync(ws, 0, o_zero_end, stream);

    k_w2frag<<<768, 256, 0, stream>>>(Wih_f, Whh_f, Wih_b, Whh_b, w2frag);
    k_deg<<<(N_EDGES + 255) / 256, 256, 0, stream>>>(head, deg);
    k_scatter<<<(N_EDGES * 64) / 256, 256, 0, stream>>>(head, tail, edge_type, rel_w, node_emb, out1);
    k_div<<<(N_NODES * DIM) / 256, 256, 0, stream>>>(out1, deg);
    k_scatter<<<(N_EDGES * 64) / 256, 256, 0, stream>>>(head, tail, edge_type, rel_w, out1, out2);
    k_lstm<<<dim3(BATCH / 32, 2), 256, 0, stream>>>(ts, w2frag, b_f, b_b, temporal);
    k_struct<<<(BATCH * DIM) / 256, 256, 0, stream>>>(node_idx, node_emb, out1, out2, deg, structb);
    k_gate<<<BATCH / 16, 256, 0, stream>>>(structb, temporal, gate_W, gate_b, merged);
    k_risk1<<<BATCH / 16, 256, 0, stream>>>(merged, risk_W1, risk_b1, t1);
    k_w2sum<<<1, 256, 0, stream>>>(risk_W2, risk_b2, w2s);
    k_final<<<BATCH / 4, 256, 0, stream>>>(t1, w2s, out);
}

// Round 2
// 701.256 us; speedup vs baseline: 3.6106x; 3.6106x over previous
//
#include <hip/hip_runtime.h>

#define N_NODES 50000
#define N_EDGES 300000
#define DIM 256
#define HID 128
#define INP 64
#define BATCH 4096
#define SEQ 50
#define SCAN_BLOCKS 196   // ceil(50000/256)

typedef float f32x4 __attribute__((ext_vector_type(4)));
typedef __bf16 bf16x8 __attribute__((ext_vector_type(8)));

__device__ __forceinline__ float sigmoidf_(float x) {
    return 1.0f / (1.0f + __expf(-x));
}
__device__ __forceinline__ float tanhf_(float x) {
    x = fmaxf(-20.0f, fminf(20.0f, x));
    float e = __expf(-2.0f * x);
    return (1.0f - e) / (1.0f + e);
}

// ---------------- GCN: counting sort by head ----------------

__global__ void k_hist(const int* __restrict__ head, int* __restrict__ deg) {
    int e = blockIdx.x * 256 + threadIdx.x;
    if (e < N_EDGES) atomicAdd(&deg[head[e]], 1);
}

__global__ void k_bsum(const int* __restrict__ deg, int* __restrict__ bsum) {
    __shared__ int red[256];
    int n = blockIdx.x * 256 + threadIdx.x;
    red[threadIdx.x] = (n < N_NODES) ? deg[n] : 0;
    __syncthreads();
    for (int st = 128; st > 0; st >>= 1) {
        if (threadIdx.x < st) red[threadIdx.x] += red[threadIdx.x + st];
        __syncthreads();
    }
    if (threadIdx.x == 0) bsum[blockIdx.x] = red[0];
}

__global__ void k_scanb(const int* __restrict__ bsum, int* __restrict__ boff) {
    __shared__ int s[256];
    int i = threadIdx.x;
    int v = (i < SCAN_BLOCKS) ? bsum[i] : 0;
    s[i] = v;
    __syncthreads();
    for (int st = 1; st < 256; st <<= 1) {
        int add = (i >= st) ? s[i - st] : 0;
        __syncthreads();
        s[i] += add;
        __syncthreads();
    }
    boff[i] = s[i] - v;   // exclusive
}

__global__ void k_scan2(const int* __restrict__ deg, const int* __restrict__ boff,
                        int* __restrict__ offsets, int* __restrict__ cursor) {
    __shared__ int s[256];
    int i = threadIdx.x;
    int n = blockIdx.x * 256 + i;
    int v = (n < N_NODES) ? deg[n] : 0;
    s[i] = v;
    __syncthreads();
    for (int st = 1; st < 256; st <<= 1) {
        int add = (i >= st) ? s[i - st] : 0;
        __syncthreads();
        s[i] += add;
        __syncthreads();
    }
    if (n < N_NODES) {
        int off = boff[blockIdx.x] + s[i] - v;
        offsets[n] = off;
        cursor[n] = off;
    }
    if (n == 0) offsets[N_NODES] = N_EDGES;
}

__global__ void k_place(const int* __restrict__ head, const int* __restrict__ tail,
                        const int* __restrict__ etype, int* __restrict__ cursor,
                        int* __restrict__ sorted) {
    int e = blockIdx.x * 256 + threadIdx.x;
    if (e >= N_EDGES) return;
    int h = head[e];
    int pos = atomicAdd(&cursor[h], 1);
    sorted[pos] = tail[e] | (etype[e] << 16);   // tail<65536, etype<32
}

// One wave per node; lane holds dims [4*lane, 4*lane+4). No atomics.
// Writes result already divided by deg (fused k_div).
__global__ void k_gather(const int* __restrict__ offsets, const int* __restrict__ sorted,
                         const float* __restrict__ relw, const float* __restrict__ src,
                         float* __restrict__ dst) {
    __shared__ __align__(16) f32x4 srel[2048];   // 32 rel x 256 dims = 32 KB
    int tid = threadIdx.x;
    for (int i = tid; i < 2048; i += 256) srel[i] = ((const f32x4*)relw)[i];
    __syncthreads();
    int w = tid >> 6, lane = tid & 63;
    int n = blockIdx.x * 4 + w;
    if (n >= N_NODES) return;
    int s = offsets[n], e = offsets[n + 1];
    f32x4 acc = (f32x4){0.f, 0.f, 0.f, 0.f};
    for (int j = s; j < e; j++) {
        int p = sorted[j];
        int t = p & 0xFFFF, r = p >> 16;
        f32x4 v = *(const f32x4*)(src + (size_t)t * DIM + lane * 4);
        f32x4 wv = srel[r * 64 + lane];
        acc += v * wv;
    }
    float inv = 1.0f / fmaxf((float)(e - s), 1.0f);
    *(f32x4*)(dst + (size_t)n * DIM + lane * 4) = acc * inv;
}

__global__ void k_struct(const int* __restrict__ nidx, const float* __restrict__ emb,
                         const float* __restrict__ out1, const float* __restrict__ out2,
                         float* __restrict__ structb) {
    int i = blockIdx.x * 256 + threadIdx.x;   // over BATCH*DIM
    int b = i >> 8, d = i & 255;
    int n = nidx[b];
    size_t o = (size_t)n * DIM + d;
    structb[i] = (emb[o] + out1[o] + out2[o]) * (1.0f / 3.0f);
}

// ---------------- BiLSTM ----------------
// Pack W = [Wih | Whh] (bf16, K=192) into MFMA B-fragment order:
// frag index = ((w*8+nt)*6+kc), within-frag = lane*8+j
// value = W2[n][k], n = gate(nt)*128 + w*32 + jt(nt)*16 + (lane&15),
//                   k = kc*32 + (lane>>4)*8 + j
__global__ void k_w2frag(const float* __restrict__ Wih_f, const float* __restrict__ Whh_f,
                         const float* __restrict__ Wih_b, const float* __restrict__ Whh_b,
                         __bf16* __restrict__ w2) {
    int idx = blockIdx.x * 256 + threadIdx.x;   // 2 * 96 * 1024 = 196608
    int dir = idx / 98304;
    int rem = idx % 98304;
    int frag = rem >> 10;
    int within = rem & 1023;
    int lane = within >> 3, j = within & 7;
    int kc = frag % 6;
    int wnt = frag / 6;
    int nt = wnt & 7, w = wnt >> 3;
    int gate = nt >> 1, jt = nt & 1;
    int n = gate * 128 + w * 32 + jt * 16 + (lane & 15);
    int k = kc * 32 + (lane >> 4) * 8 + j;
    const float* Wih = dir ? Wih_b : Wih_f;
    const float* Whh = dir ? Whh_b : Whh_f;
    float v = (k < 64) ? Wih[n * 64 + k] : Whh[n * 128 + (k - 64)];
    w2[idx] = (__bf16)v;
}

// Block = 4 waves, 32 batch samples, one direction, all 50 steps.
// Wave w owns hidden units j in [w*32, w*32+32) for ALL four gates.
__launch_bounds__(256)
__global__ void k_lstm(const float* __restrict__ ts, const __bf16* __restrict__ w2frag,
                       const float* __restrict__ b_f, const float* __restrict__ b_b,
                       float* __restrict__ temporal) {
    int dir = blockIdx.y;
    int btile = blockIdx.x;    // 0..127
    int tid = threadIdx.x;
    int w = tid >> 6;
    int lane = tid & 63;
    int col = lane & 15, quad = lane >> 4;

    __shared__ __align__(16) __bf16 A[32][200];   // [m][k], K=192 padded to 200

    // zero h region (k = 64..191)
    for (int i = tid; i < 32 * 128; i += 256) {
        A[i >> 7][64 + (i & 127)] = (__bf16)0.0f;
    }

    const float* bias = dir ? b_b : b_f;
    float bv[8];
#pragma unroll
    for (int nt = 0; nt < 8; nt++) {
        int n = (nt >> 1) * 128 + w * 32 + (nt & 1) * 16 + col;
        bv[nt] = bias[n];
    }
    const __bf16* wbase = w2frag + (size_t)dir * 98304 + (size_t)w * 49152;

    f32x4 c_reg[4], hsum[4];
#pragma unroll
    for (int s = 0; s < 4; s++) {
        c_reg[s] = (f32x4){0.f, 0.f, 0.f, 0.f};
        hsum[s]  = (f32x4){0.f, 0.f, 0.f, 0.f};
    }
    __syncthreads();

    for (int t = 0; t < SEQ; t++) {
        int tt = dir ? (SEQ - 1 - t) : t;
        // stage x_t: 32 rows x 64 cols; thread -> row=tid>>3, cols [(tid&7)*8, +8)
        {
            int m = tid >> 3, c8 = (tid & 7) * 8;
            int b = btile * 32 + m;
            const float* xp = ts + ((size_t)b * SEQ + tt) * INP + c8;
            f32x4 x0 = *(const f32x4*)(xp);
            f32x4 x1 = *(const f32x4*)(xp + 4);
            bf16x8 xv;
            xv[0] = (__bf16)x0.x; xv[1] = (__bf16)x0.y;
            xv[2] = (__bf16)x0.z; xv[3] = (__bf16)x0.w;
            xv[4] = (__bf16)x1.x; xv[5] = (__bf16)x1.y;
            xv[6] = (__bf16)x1.z; xv[7] = (__bf16)x1.w;
            *(bf16x8*)&A[m][c8] = xv;
        }
        __syncthreads();

        f32x4 acc[16];
#pragma unroll
        for (int nt = 0; nt < 8; nt++) {
            f32x4 z = (f32x4){bv[nt], bv[nt], bv[nt], bv[nt]};
            acc[nt * 2] = z;
            acc[nt * 2 + 1] = z;
        }
#pragma unroll
        for (int kc = 0; kc < 6; kc++) {
            bf16x8 a0 = *(const bf16x8*)&A[col][kc * 32 + quad * 8];
            bf16x8 a1 = *(const bf16x8*)&A[16 + col][kc * 32 + quad * 8];
#pragma unroll
            for (int nt = 0; nt < 8; nt++) {
                bf16x8 bfrag = *(const bf16x8*)(wbase + ((nt * 6 + kc) << 10) + lane * 8);
                acc[nt * 2]     = __builtin_amdgcn_mfma_f32_16x16x32_bf16(a0, bfrag, acc[nt * 2], 0, 0, 0);
                acc[nt * 2 + 1] = __builtin_amdgcn_mfma_f32_16x16x32_bf16(a1, bfrag, acc[nt * 2 + 1], 0, 0, 0);
            }
        }
        __syncthreads();   // everyone's A reads done before h_t overwrite

        // cell update: lane owns (b,j) pairs; i/f/g/o in same lane, same reg idx
#pragma unroll
        for (int m = 0; m < 2; m++) {
#pragma unroll
            for (int jt = 0; jt < 2; jt++) {
                int s = m * 2 + jt;
#pragma unroll
                for (int r = 0; r < 4; r++) {
                    float iv = acc[(0 * 2 + jt) * 2 + m][r];
                    float fv = acc[(1 * 2 + jt) * 2 + m][r];
                    float gv = acc[(2 * 2 + jt) * 2 + m][r];
                    float ov = acc[(3 * 2 + jt) * 2 + m][r];
                    float c = sigmoidf_(fv) * c_reg[s][r] + sigmoidf_(iv) * tanhf_(gv);
                    float h = sigmoidf_(ov) * tanhf_(c);
                    c_reg[s][r] = c;
                    hsum[s][r] += h;
                    A[m * 16 + quad * 4 + r][64 + w * 32 + jt * 16 + col] = (__bf16)h;
                }
            }
        }
    }

    // temporal[b][dir*128 + j] = mean over t of h
#pragma unroll
    for (int m = 0; m < 2; m++) {
#pragma unroll
        for (int jt = 0; jt < 2; jt++) {
            int s = m * 2 + jt;
#pragma unroll
            for (int r = 0; r < 4; r++) {
                int b = btile * 32 + m * 16 + quad * 4 + r;
                int j = w * 32 + jt * 16 + col;
                temporal[(size_t)b * 256 + dir * 128 + j] = hsum[s][r] * (1.0f / SEQ);
            }
        }
    }
}

// ---------------- Head ----------------

__global__ void k_gate(const float* __restrict__ structb, const float* __restrict__ temporal,
                       const float* __restrict__ gate_W, const float* __restrict__ gate_b,
                       float* __restrict__ merged) {
    int bt = blockIdx.x;      // 256 blocks x 16 samples
    int n = threadIdx.x;      // output unit
    __shared__ __align__(16) float cat[16][512];
    for (int i = n; i < 16 * 512; i += 256) {
        int bb = i >> 9, k = i & 511;
        int b = bt * 16 + bb;
        cat[bb][k] = (k < 256) ? structb[(size_t)b * 256 + k]
                               : temporal[(size_t)b * 256 + (k - 256)];
    }
    __syncthreads();
    float acc[16];
#pragma unroll
    for (int bb = 0; bb < 16; bb++) acc[bb] = gate_b[n];
    const float* wrow = gate_W + (size_t)n * 512;
    for (int k4 = 0; k4 < 512; k4 += 4) {
        f32x4 wv = *(const f32x4*)(wrow + k4);
#pragma unroll
        for (int bb = 0; bb < 16; bb++) {
            f32x4 cv = *(const f32x4*)&cat[bb][k4];
            acc[bb] += cv.x * wv.x + cv.y * wv.y + cv.z * wv.z + cv.w * wv.w;
        }
    }
    int b0 = bt * 16;
#pragma unroll
    for (int bb = 0; bb < 16; bb++) {
        float g = sigmoidf_(acc[bb]);
        float s = structb[(size_t)(b0 + bb) * 256 + n];
        float tm = temporal[(size_t)(b0 + bb) * 256 + n];
        merged[(size_t)(b0 + bb) * 256 + n] = g * s + (1.0f - g) * tm;
    }
}

__global__ void k_risk1(const float* __restrict__ merged, const float* __restrict__ W1,
                        const float* __restrict__ b1, float* __restrict__ t1) {
    int bt = blockIdx.x;      // 256 blocks x 16 samples
    int n = threadIdx.x;
    __shared__ __align__(16) float mt[16][256];
    for (int i = n; i < 16 * 256; i += 256) {
        int bb = i >> 8, k = i & 255;
        mt[bb][k] = merged[(size_t)(bt * 16 + bb) * 256 + k];
    }
    __syncthreads();
    float acc[16];
#pragma unroll
    for (int bb = 0; bb < 16; bb++) acc[bb] = b1[n];
    const float* wrow = W1 + (size_t)n * 256;
    for (int k4 = 0; k4 < 256; k4 += 4) {
        f32x4 wv = *(const f32x4*)(wrow + k4);
#pragma unroll
        for (int bb = 0; bb < 16; bb++) {
            f32x4 cv = *(const f32x4*)&mt[bb][k4];
            acc[bb] += cv.x * wv.x + cv.y * wv.y + cv.z * wv.z + cv.w * wv.w;
        }
    }
#pragma unroll
    for (int bb = 0; bb < 16; bb++) {
        t1[(size_t)(bt * 16 + bb) * 256 + n] = tanhf_(acc[bb]);
    }
}

// risk.sum(-1) collapses: sum_n(t1@W2^T + b2) = t1 . colsum(W2) + sum(b2)
__global__ void k_w2sum(const float* __restrict__ W2, const float* __restrict__ b2,
                        float* __restrict__ w2s) {
    int k = threadIdx.x;
    float s = 0.0f;
    for (int n = 0; n < 256; n++) s += W2[(size_t)n * 256 + k];
    w2s[k] = s;
    __shared__ float red[256];
    red[k] = b2[k];
    __syncthreads();
    for (int st = 128; st > 0; st >>= 1) {
        if (k < st) red[k] += red[k + st];
        __syncthreads();
    }
    if (k == 0) w2s[256] = red[0];
}

__global__ void k_final(const float* __restrict__ t1, const float* __restrict__ w2s,
                        float* __restrict__ out) {
    int b = (blockIdx.x * 256 + threadIdx.x) >> 6;   // one wave per sample
    int lane = threadIdx.x & 63;
    const float* row = t1 + (size_t)b * 256;
    float s = 0.0f;
#pragma unroll
    for (int q = 0; q < 4; q++) s += row[lane + q * 64] * w2s[lane + q * 64];
#pragma unroll
    for (int off = 32; off > 0; off >>= 1) s += __shfl_down(s, off, 64);
    if (lane == 0) out[b] = sigmoidf_(s + w2s[256]);
}

// ---------------- launch ----------------

extern "C" void kernel_launch(void* const* d_in, const int* in_sizes, int n_in,
                              void* d_out, int out_size, void* d_ws, size_t ws_size,
                              hipStream_t stream) {
    const float* ts       = (const float*)d_in[0];
    const float* node_emb = (const float*)d_in[1];
    const float* rel_w    = (const float*)d_in[2];
    const float* gate_W   = (const float*)d_in[3];
    const float* gate_b   = (const float*)d_in[4];
    const float* risk_W1  = (const float*)d_in[5];
    const float* risk_b1  = (const float*)d_in[6];
    const float* risk_W2  = (const float*)d_in[7];
    const float* risk_b2  = (const float*)d_in[8];
    const float* Wih_f    = (const float*)d_in[9];
    const float* Whh_f    = (const float*)d_in[10];
    const float* b_f      = (const float*)d_in[11];
    const float* Wih_b    = (const float*)d_in[12];
    const float* Whh_b    = (const float*)d_in[13];
    const float* b_b      = (const float*)d_in[14];
    const int* edge_index = (const int*)d_in[15];
    const int* edge_type  = (const int*)d_in[16];
    const int* node_idx   = (const int*)d_in[17];
    const int* head = edge_index;
    const int* tail = edge_index + N_EDGES;
    float* out = (float*)d_out;

    char* ws = (char*)d_ws;
    // int sort scratch (deg zeroed by memset)
    const size_t o_deg      = 0;                            // 50000 int
    const size_t o_deg_end  = 200704;
    const size_t o_bsum     = o_deg_end;                    // 196 int -> pad 1024
    const size_t o_boff     = o_bsum + 1024;                // 256 int
    const size_t o_offsets  = o_boff + 1024;                // 50001 int -> pad 200960
    const size_t o_cursor   = o_offsets + 200960;           // 50000 int
    const size_t o_sorted   = o_cursor + 200704;            // 300000 int
    const size_t o_out1     = o_sorted + 1200128;           // 51,200,000 B
    const size_t o_out2     = o_out1 + 51200000;
    const size_t o_temporal = o_out2 + 51200000;            // 4 MB
    const size_t o_struct   = o_temporal + 4194304;
    const size_t o_merged   = o_struct + 4194304;
    const size_t o_t1       = o_merged + 4194304;
    const size_t o_w2s      = o_t1 + 4194304;
    const size_t o_w2frag   = o_w2s + 2048;

    int*    deg      = (int*)(ws + o_deg);
    int*    bsum     = (int*)(ws + o_bsum);
    int*    boff     = (int*)(ws + o_boff);
    int*    offsets  = (int*)(ws + o_offsets);
    int*    cursor   = (int*)(ws + o_cursor);
    int*    sorted   = (int*)(ws + o_sorted);
    float*  out1     = (float*)(ws + o_out1);
    float*  out2     = (float*)(ws + o_out2);
    float*  temporal = (float*)(ws + o_temporal);
    float*  structb  = (float*)(ws + o_struct);
    float*  merged   = (float*)(ws + o_merged);
    float*  t1       = (float*)(ws + o_t1);
    float*  w2s      = (float*)(ws + o_w2s);
    __bf16* w2frag   = (__bf16*)(ws + o_w2frag);

    hipMemsetAsync(deg, 0, N_NODES * sizeof(int), stream);

    k_w2frag<<<768, 256, 0, stream>>>(Wih_f, Whh_f, Wih_b, Whh_b, w2frag);
    k_hist<<<(N_EDGES + 255) / 256, 256, 0, stream>>>(head, deg);
    k_bsum<<<SCAN_BLOCKS, 256, 0, stream>>>(deg, bsum);
    k_scanb<<<1, 256, 0, stream>>>(bsum, boff);
    k_scan2<<<SCAN_BLOCKS, 256, 0, stream>>>(deg, boff, offsets, cursor);
    k_place<<<(N_EDGES + 255) / 256, 256, 0, stream>>>(head, tail, edge_type, cursor, sorted);
    k_gather<<<(N_NODES + 3) / 4, 256, 0, stream>>>(offsets, sorted, rel_w, node_emb, out1);
    k_gather<<<(N_NODES + 3) / 4, 256, 0, stream>>>(offsets, sorted, rel_w, out1, out2);
    k_lstm<<<dim3(BATCH / 32, 2), 256, 0, stream>>>(ts, w2frag, b_f, b_b, temporal);
    k_struct<<<(BATCH * DIM) / 256, 256, 0, stream>>>(node_idx, node_emb, out1, out2, structb);
    k_gate<<<BATCH / 16, 256, 0, stream>>>(structb, temporal, gate_W, gate_b, merged);
    k_risk1<<<BATCH / 16, 256, 0, stream>>>(merged, risk_W1, risk_b1, t1);
    k_w2sum<<<1, 256, 0, stream>>>(risk_W2, risk_b2, w2s);
    k_final<<<BATCH / 4, 256, 0, stream>>>(t1, w2s, out);
}

// Round 3
// 563.859 us; speedup vs baseline: 4.4904x; 1.2437x over previous
//
#include <hip/hip_runtime.h>

#define N_NODES 50000
#define N_EDGES 300000
#define DIM 256
#define HID 128
#define INP 64
#define BATCH 4096
#define SEQ 50
#define SCAN_BLOCKS 196   // ceil(50000/256)

typedef float f32x4 __attribute__((ext_vector_type(4)));
typedef __bf16 bf16x4 __attribute__((ext_vector_type(4)));
typedef __bf16 bf16x8 __attribute__((ext_vector_type(8)));

// fast activations: v_rcp_f32 instead of IEEE divide (~1 ulp, inf-safe)
__device__ __forceinline__ float sigmoidf_(float x) {
    return __builtin_amdgcn_rcpf(1.0f + __expf(-x));
}
__device__ __forceinline__ float tanhf_(float x) {
    return 1.0f - 2.0f * __builtin_amdgcn_rcpf(1.0f + __expf(2.0f * x));
}

// ---------------- GCN: counting sort by head ----------------

__global__ void k_hist(const int* __restrict__ head, int* __restrict__ deg) {
    int e = blockIdx.x * 256 + threadIdx.x;
    if (e < N_EDGES) atomicAdd(&deg[head[e]], 1);
}

__global__ void k_bsum(const int* __restrict__ deg, int* __restrict__ bsum) {
    __shared__ int red[256];
    int n = blockIdx.x * 256 + threadIdx.x;
    red[threadIdx.x] = (n < N_NODES) ? deg[n] : 0;
    __syncthreads();
    for (int st = 128; st > 0; st >>= 1) {
        if (threadIdx.x < st) red[threadIdx.x] += red[threadIdx.x + st];
        __syncthreads();
    }
    if (threadIdx.x == 0) bsum[blockIdx.x] = red[0];
}

__global__ void k_scanb(const int* __restrict__ bsum, int* __restrict__ boff) {
    __shared__ int s[256];
    int i = threadIdx.x;
    int v = (i < SCAN_BLOCKS) ? bsum[i] : 0;
    s[i] = v;
    __syncthreads();
    for (int st = 1; st < 256; st <<= 1) {
        int add = (i >= st) ? s[i - st] : 0;
        __syncthreads();
        s[i] += add;
        __syncthreads();
    }
    boff[i] = s[i] - v;   // exclusive
}

__global__ void k_scan2(const int* __restrict__ deg, const int* __restrict__ boff,
                        int* __restrict__ offsets, int* __restrict__ cursor) {
    __shared__ int s[256];
    int i = threadIdx.x;
    int n = blockIdx.x * 256 + i;
    int v = (n < N_NODES) ? deg[n] : 0;
    s[i] = v;
    __syncthreads();
    for (int st = 1; st < 256; st <<= 1) {
        int add = (i >= st) ? s[i - st] : 0;
        __syncthreads();
        s[i] += add;
        __syncthreads();
    }
    if (n < N_NODES) {
        int off = boff[blockIdx.x] + s[i] - v;
        offsets[n] = off;
        cursor[n] = off;
    }
    if (n == 0) offsets[N_NODES] = N_EDGES;
}

__global__ void k_place(const int* __restrict__ head, const int* __restrict__ tail,
                        const int* __restrict__ etype, int* __restrict__ cursor,
                        int* __restrict__ sorted) {
    int e = blockIdx.x * 256 + threadIdx.x;
    if (e >= N_EDGES) return;
    int h = head[e];
    int pos = atomicAdd(&cursor[h], 1);
    sorted[pos] = tail[e] | (etype[e] << 16);   // tail<65536, etype<32
}

// One wave per node; lane holds dims [4*lane, 4*lane+4). No atomics.
// 2-edge unroll for load ILP. Writes result already divided by deg.
__global__ void k_gather(const int* __restrict__ offsets, const int* __restrict__ sorted,
                         const float* __restrict__ relw, const float* __restrict__ src,
                         float* __restrict__ dst) {
    __shared__ __align__(16) f32x4 srel[2048];   // 32 rel x 256 dims = 32 KB
    int tid = threadIdx.x;
    for (int i = tid; i < 2048; i += 256) srel[i] = ((const f32x4*)relw)[i];
    __syncthreads();
    int w = tid >> 6, lane = tid & 63;
    int n = blockIdx.x * 4 + w;
    if (n >= N_NODES) return;
    int s = offsets[n], e = offsets[n + 1];
    f32x4 acc0 = (f32x4){0.f, 0.f, 0.f, 0.f};
    f32x4 acc1 = (f32x4){0.f, 0.f, 0.f, 0.f};
    int j = s;
    for (; j + 2 <= e; j += 2) {
        int p0 = sorted[j], p1 = sorted[j + 1];
        f32x4 v0 = *(const f32x4*)(src + (size_t)(p0 & 0xFFFF) * DIM + lane * 4);
        f32x4 v1 = *(const f32x4*)(src + (size_t)(p1 & 0xFFFF) * DIM + lane * 4);
        acc0 += v0 * srel[(p0 >> 16) * 64 + lane];
        acc1 += v1 * srel[(p1 >> 16) * 64 + lane];
    }
    if (j < e) {
        int p0 = sorted[j];
        f32x4 v0 = *(const f32x4*)(src + (size_t)(p0 & 0xFFFF) * DIM + lane * 4);
        acc0 += v0 * srel[(p0 >> 16) * 64 + lane];
    }
    acc0 += acc1;
    float inv = 1.0f / fmaxf((float)(e - s), 1.0f);
    *(f32x4*)(dst + (size_t)n * DIM + lane * 4) = acc0 * inv;
}

__global__ void k_struct(const int* __restrict__ nidx, const float* __restrict__ emb,
                         const float* __restrict__ out1, const float* __restrict__ out2,
                         float* __restrict__ structb) {
    int i = blockIdx.x * 256 + threadIdx.x;   // over BATCH*DIM
    int b = i >> 8, d = i & 255;
    int n = nidx[b];
    size_t o = (size_t)n * DIM + d;
    structb[i] = (emb[o] + out1[o] + out2[o]) * (1.0f / 3.0f);
}

// ---------------- BiLSTM ----------------
// Pack W = [Wih | Whh] (bf16, K=192) into MFMA B-fragment order, 512-elem frags:
// per dir: frag = (w*4+g)*6+kc  (w=wave 0..7, g=gate 0..3, kc=0..5)
// within-frag = lane*8+j ; value = W[n][k],
//   n = g*128 + w*16 + (lane&15),  k = kc*32 + (lane>>4)*8 + j
__global__ void k_w2frag(const float* __restrict__ Wih_f, const float* __restrict__ Whh_f,
                         const float* __restrict__ Wih_b, const float* __restrict__ Whh_b,
                         __bf16* __restrict__ w2) {
    int idx = blockIdx.x * 256 + threadIdx.x;   // 2 * 192 * 512 = 196608
    int dir = idx / 98304;
    int rem = idx % 98304;
    int frag = rem >> 9;        // 0..191
    int within = rem & 511;
    int lane = within >> 3, j = within & 7;
    int kc = frag % 6;
    int wg = frag / 6;          // 0..31
    int g = wg & 3, w = wg >> 2;
    int n = g * 128 + w * 16 + (lane & 15);
    int k = kc * 32 + (lane >> 4) * 8 + j;
    const float* Wih = dir ? Wih_b : Wih_f;
    const float* Whh = dir ? Whh_b : Whh_f;
    float v = (k < 64) ? Wih[n * 64 + k] : Whh[n * 128 + (k - 64)];
    w2[idx] = (__bf16)v;
}

// Block = 8 waves (512 threads), 32 batch samples, one direction, all 50 steps.
// Wave w owns hidden cols j in [w*16, w*16+16) for ALL four gates.
// Grid 256 blocks -> 1 block/CU, 8 waves/CU = 2 waves/SIMD (MFMA/VALU overlap).
__launch_bounds__(512)
__global__ void k_lstm(const float* __restrict__ ts, const __bf16* __restrict__ w2frag,
                       const float* __restrict__ b_f, const float* __restrict__ b_b,
                       float* __restrict__ temporal) {
    int dir = blockIdx.y;
    int btile = blockIdx.x;    // 0..127
    int tid = threadIdx.x;
    int w = tid >> 6;          // wave 0..7
    int lane = tid & 63;
    int col = lane & 15, quad = lane >> 4;

    __shared__ __align__(16) __bf16 A[32][200];   // [m][k], K=192 padded to 200

    // zero h region (k = 64..191)
    for (int i = tid; i < 32 * 128; i += 512) {
        A[i >> 7][64 + (i & 127)] = (__bf16)0.0f;
    }

    const float* bias = dir ? b_b : b_f;
    float bv[4];
#pragma unroll
    for (int g = 0; g < 4; g++) {
        bv[g] = bias[g * 128 + w * 16 + col];
    }
    const __bf16* wbase = w2frag + (size_t)dir * 98304 + (size_t)w * 12288;

    f32x4 c_reg[2], hsum[2];
#pragma unroll
    for (int s = 0; s < 2; s++) {
        c_reg[s] = (f32x4){0.f, 0.f, 0.f, 0.f};
        hsum[s]  = (f32x4){0.f, 0.f, 0.f, 0.f};
    }
    __syncthreads();

    for (int t = 0; t < SEQ; t++) {
        int tt = dir ? (SEQ - 1 - t) : t;
        // stage x_t: 32 rows x 64 cols; thread -> row=tid>>4, cols [(tid&15)*4, +4)
        {
            int m = tid >> 4, c4 = (tid & 15) * 4;
            int b = btile * 32 + m;
            const float* xp = ts + ((size_t)b * SEQ + tt) * INP + c4;
            f32x4 x0 = *(const f32x4*)(xp);
            bf16x4 xv;
            xv[0] = (__bf16)x0.x; xv[1] = (__bf16)x0.y;
            xv[2] = (__bf16)x0.z; xv[3] = (__bf16)x0.w;
            *(bf16x4*)&A[m][c4] = xv;
        }
        __syncthreads();

        f32x4 acc[8];
#pragma unroll
        for (int g = 0; g < 4; g++) {
            f32x4 z = (f32x4){bv[g], bv[g], bv[g], bv[g]};
            acc[g * 2] = z;
            acc[g * 2 + 1] = z;
        }
#pragma unroll
        for (int kc = 0; kc < 6; kc++) {
            bf16x8 a0 = *(const bf16x8*)&A[col][kc * 32 + quad * 8];
            bf16x8 a1 = *(const bf16x8*)&A[16 + col][kc * 32 + quad * 8];
#pragma unroll
            for (int g = 0; g < 4; g++) {
                bf16x8 bfrag = *(const bf16x8*)(wbase + ((g * 6 + kc) << 9) + lane * 8);
                acc[g * 2]     = __builtin_amdgcn_mfma_f32_16x16x32_bf16(a0, bfrag, acc[g * 2], 0, 0, 0);
                acc[g * 2 + 1] = __builtin_amdgcn_mfma_f32_16x16x32_bf16(a1, bfrag, acc[g * 2 + 1], 0, 0, 0);
            }
        }
        __syncthreads();   // everyone's A reads done before h_t overwrite

        // cell update: lane owns (b,j) pairs; i/f/g/o same lane, same reg idx
#pragma unroll
        for (int m = 0; m < 2; m++) {
#pragma unroll
            for (int r = 0; r < 4; r++) {
                float iv = acc[0 * 2 + m][r];
                float fv = acc[1 * 2 + m][r];
                float gv = acc[2 * 2 + m][r];
                float ov = acc[3 * 2 + m][r];
                float c = sigmoidf_(fv) * c_reg[m][r] + sigmoidf_(iv) * tanhf_(gv);
                float h = sigmoidf_(ov) * tanhf_(c);
                c_reg[m][r] = c;
                hsum[m][r] += h;
                A[m * 16 + quad * 4 + r][64 + w * 16 + col] = (__bf16)h;
            }
        }
    }

    // temporal[b][dir*128 + j] = mean over t of h
#pragma unroll
    for (int m = 0; m < 2; m++) {
#pragma unroll
        for (int r = 0; r < 4; r++) {
            int b = btile * 32 + m * 16 + quad * 4 + r;
            int j = w * 16 + col;
            temporal[(size_t)b * 256 + dir * 128 + j] = hsum[m][r] * (1.0f / SEQ);
        }
    }
}

// ---------------- Head ----------------

__global__ void k_gate(const float* __restrict__ structb, const float* __restrict__ temporal,
                       const float* __restrict__ gate_W, const float* __restrict__ gate_b,
                       float* __restrict__ merged) {
    int bt = blockIdx.x;      // 256 blocks x 16 samples
    int n = threadIdx.x;      // output unit
    __shared__ __align__(16) float cat[16][512];
    for (int i = n; i < 16 * 512; i += 256) {
        int bb = i >> 9, k = i & 511;
        int b = bt * 16 + bb;
        cat[bb][k] = (k < 256) ? structb[(size_t)b * 256 + k]
                               : temporal[(size_t)b * 256 + (k - 256)];
    }
    __syncthreads();
    float acc[16];
#pragma unroll
    for (int bb = 0; bb < 16; bb++) acc[bb] = gate_b[n];
    const float* wrow = gate_W + (size_t)n * 512;
    for (int k4 = 0; k4 < 512; k4 += 4) {
        f32x4 wv = *(const f32x4*)(wrow + k4);
#pragma unroll
        for (int bb = 0; bb < 16; bb++) {
            f32x4 cv = *(const f32x4*)&cat[bb][k4];
            acc[bb] += cv.x * wv.x + cv.y * wv.y + cv.z * wv.z + cv.w * wv.w;
        }
    }
    int b0 = bt * 16;
#pragma unroll
    for (int bb = 0; bb < 16; bb++) {
        float g = sigmoidf_(acc[bb]);
        float s = structb[(size_t)(b0 + bb) * 256 + n];
        float tm = temporal[(size_t)(b0 + bb) * 256 + n];
        merged[(size_t)(b0 + bb) * 256 + n] = g * s + (1.0f - g) * tm;
    }
}

__global__ void k_risk1(const float* __restrict__ merged, const float* __restrict__ W1,
                        const float* __restrict__ b1, float* __restrict__ t1) {
    int bt = blockIdx.x;      // 256 blocks x 16 samples
    int n = threadIdx.x;
    __shared__ __align__(16) float mt[16][256];
    for (int i = n; i < 16 * 256; i += 256) {
        int bb = i >> 8, k = i & 255;
        mt[bb][k] = merged[(size_t)(bt * 16 + bb) * 256 + k];
    }
    __syncthreads();
    float acc[16];
#pragma unroll
    for (int bb = 0; bb < 16; bb++) acc[bb] = b1[n];
    const float* wrow = W1 + (size_t)n * 256;
    for (int k4 = 0; k4 < 256; k4 += 4) {
        f32x4 wv = *(const f32x4*)(wrow + k4);
#pragma unroll
        for (int bb = 0; bb < 16; bb++) {
            f32x4 cv = *(const f32x4*)&mt[bb][k4];
            acc[bb] += cv.x * wv.x + cv.y * wv.y + cv.z * wv.z + cv.w * wv.w;
        }
    }
#pragma unroll
    for (int bb = 0; bb < 16; bb++) {
        t1[(size_t)(bt * 16 + bb) * 256 + n] = tanhf_(acc[bb]);
    }
}

// risk.sum(-1) collapses: sum_n(t1@W2^T + b2) = t1 . colsum(W2) + sum(b2)
__global__ void k_w2sum(const float* __restrict__ W2, const float* __restrict__ b2,
                        float* __restrict__ w2s) {
    int k = threadIdx.x;
    float s = 0.0f;
    for (int n = 0; n < 256; n++) s += W2[(size_t)n * 256 + k];
    w2s[k] = s;
    __shared__ float red[256];
    red[k] = b2[k];
    __syncthreads();
    for (int st = 128; st > 0; st >>= 1) {
        if (k < st) red[k] += red[k + st];
        __syncthreads();
    }
    if (k == 0) w2s[256] = red[0];
}

__global__ void k_final(const float* __restrict__ t1, const float* __restrict__ w2s,
                        float* __restrict__ out) {
    int b = (blockIdx.x * 256 + threadIdx.x) >> 6;   // one wave per sample
    int lane = threadIdx.x & 63;
    const float* row = t1 + (size_t)b * 256;
    float s = 0.0f;
#pragma unroll
    for (int q = 0; q < 4; q++) s += row[lane + q * 64] * w2s[lane + q * 64];
#pragma unroll
    for (int off = 32; off > 0; off >>= 1) s += __shfl_down(s, off, 64);
    if (lane == 0) out[b] = sigmoidf_(s + w2s[256]);
}

// ---------------- launch ----------------

extern "C" void kernel_launch(void* const* d_in, const int* in_sizes, int n_in,
                              void* d_out, int out_size, void* d_ws, size_t ws_size,
                              hipStream_t stream) {
    const float* ts       = (const float*)d_in[0];
    const float* node_emb = (const float*)d_in[1];
    const float* rel_w    = (const float*)d_in[2];
    const float* gate_W   = (const float*)d_in[3];
    const float* gate_b   = (const float*)d_in[4];
    const float* risk_W1  = (const float*)d_in[5];
    const float* risk_b1  = (const float*)d_in[6];
    const float* risk_W2  = (const float*)d_in[7];
    const float* risk_b2  = (const float*)d_in[8];
    const float* Wih_f    = (const float*)d_in[9];
    const float* Whh_f    = (const float*)d_in[10];
    const float* b_f      = (const float*)d_in[11];
    const float* Wih_b    = (const float*)d_in[12];
    const float* Whh_b    = (const float*)d_in[13];
    const float* b_b      = (const float*)d_in[14];
    const int* edge_index = (const int*)d_in[15];
    const int* edge_type  = (const int*)d_in[16];
    const int* node_idx   = (const int*)d_in[17];
    const int* head = edge_index;
    const int* tail = edge_index + N_EDGES;
    float* out = (float*)d_out;

    char* ws = (char*)d_ws;
    const size_t o_deg      = 0;                            // 50000 int
    const size_t o_deg_end  = 200704;
    const size_t o_bsum     = o_deg_end;                    // 196 int -> pad 1024
    const size_t o_boff     = o_bsum + 1024;                // 256 int
    const size_t o_offsets  = o_boff + 1024;                // 50001 int -> pad 200960
    const size_t o_cursor   = o_offsets + 200960;           // 50000 int
    const size_t o_sorted   = o_cursor + 200704;            // 300000 int
    const size_t o_out1     = o_sorted + 1200128;           // 51,200,000 B
    const size_t o_out2     = o_out1 + 51200000;
    const size_t o_temporal = o_out2 + 51200000;            // 4 MB
    const size_t o_struct   = o_temporal + 4194304;
    const size_t o_merged   = o_struct + 4194304;
    const size_t o_t1       = o_merged + 4194304;
    const size_t o_w2s      = o_t1 + 4194304;
    const size_t o_w2frag   = o_w2s + 2048;                 // 393216 B

    int*    deg      = (int*)(ws + o_deg);
    int*    bsum     = (int*)(ws + o_bsum);
    int*    boff     = (int*)(ws + o_boff);
    int*    offsets  = (int*)(ws + o_offsets);
    int*    cursor   = (int*)(ws + o_cursor);
    int*    sorted   = (int*)(ws + o_sorted);
    float*  out1     = (float*)(ws + o_out1);
    float*  out2     = (float*)(ws + o_out2);
    float*  temporal = (float*)(ws + o_temporal);
    float*  structb  = (float*)(ws + o_struct);
    float*  merged   = (float*)(ws + o_merged);
    float*  t1       = (float*)(ws + o_t1);
    float*  w2s      = (float*)(ws + o_w2s);
    __bf16* w2frag   = (__bf16*)(ws + o_w2frag);

    hipMemsetAsync(deg, 0, N_NODES * sizeof(int), stream);

    k_w2frag<<<768, 256, 0, stream>>>(Wih_f, Whh_f, Wih_b, Whh_b, w2frag);
    k_hist<<<(N_EDGES + 255) / 256, 256, 0, stream>>>(head, deg);
    k_bsum<<<SCAN_BLOCKS, 256, 0, stream>>>(deg, bsum);
    k_scanb<<<1, 256, 0, stream>>>(bsum, boff);
    k_scan2<<<SCAN_BLOCKS, 256, 0, stream>>>(deg, boff, offsets, cursor);
    k_place<<<(N_EDGES + 255) / 256, 256, 0, stream>>>(head, tail, edge_type, cursor, sorted);
    k_gather<<<(N_NODES + 3) / 4, 256, 0, stream>>>(offsets, sorted, rel_w, node_emb, out1);
    k_gather<<<(N_NODES + 3) / 4, 256, 0, stream>>>(offsets, sorted, rel_w, out1, out2);
    k_lstm<<<dim3(BATCH / 32, 2), 512, 0, stream>>>(ts, w2frag, b_f, b_b, temporal);
    k_struct<<<(BATCH * DIM) / 256, 256, 0, stream>>>(node_idx, node_emb, out1, out2, structb);
    k_gate<<<BATCH / 16, 256, 0, stream>>>(structb, temporal, gate_W, gate_b, merged);
    k_risk1<<<BATCH / 16, 256, 0, stream>>>(merged, risk_W1, risk_b1, t1);
    k_w2sum<<<1, 256, 0, stream>>>(risk_W2, risk_b2, w2s);
    k_final<<<BATCH / 4, 256, 0, stream>>>(t1, w2s, out);
}

// Round 4
// 473.845 us; speedup vs baseline: 5.3435x; 1.1900x over previous
//
#include <hip/hip_runtime.h>

#define N_NODES 50000
#define N_EDGES 300000
#define DIM 256
#define HID 128
#define INP 64
#define BATCH 4096
#define SEQ 50
#define SCAN_BLOCKS 196   // ceil(50000/256)

typedef float f32x4 __attribute__((ext_vector_type(4)));
typedef __bf16 bf16x4 __attribute__((ext_vector_type(4)));
typedef __bf16 bf16x8 __attribute__((ext_vector_type(8)));

// fast activations: v_rcp_f32 instead of IEEE divide (~1 ulp, inf-safe)
__device__ __forceinline__ float sigmoidf_(float x) {
    return __builtin_amdgcn_rcpf(1.0f + __expf(-x));
}
__device__ __forceinline__ float tanhf_(float x) {
    return 1.0f - 2.0f * __builtin_amdgcn_rcpf(1.0f + __expf(2.0f * x));
}

// ---------------- GCN: counting sort by head ----------------

__global__ void k_hist(const int* __restrict__ head, int* __restrict__ deg) {
    int e = blockIdx.x * 256 + threadIdx.x;
    if (e < N_EDGES) atomicAdd(&deg[head[e]], 1);
}

__global__ void k_bsum(const int* __restrict__ deg, int* __restrict__ bsum) {
    __shared__ int red[256];
    int n = blockIdx.x * 256 + threadIdx.x;
    red[threadIdx.x] = (n < N_NODES) ? deg[n] : 0;
    __syncthreads();
    for (int st = 128; st > 0; st >>= 1) {
        if (threadIdx.x < st) red[threadIdx.x] += red[threadIdx.x + st];
        __syncthreads();
    }
    if (threadIdx.x == 0) bsum[blockIdx.x] = red[0];
}

__global__ void k_scanb(const int* __restrict__ bsum, int* __restrict__ boff) {
    __shared__ int s[256];
    int i = threadIdx.x;
    int v = (i < SCAN_BLOCKS) ? bsum[i] : 0;
    s[i] = v;
    __syncthreads();
    for (int st = 1; st < 256; st <<= 1) {
        int add = (i >= st) ? s[i - st] : 0;
        __syncthreads();
        s[i] += add;
        __syncthreads();
    }
    boff[i] = s[i] - v;   // exclusive
}

__global__ void k_scan2(const int* __restrict__ deg, const int* __restrict__ boff,
                        int* __restrict__ offsets, int* __restrict__ cursor) {
    __shared__ int s[256];
    int i = threadIdx.x;
    int n = blockIdx.x * 256 + i;
    int v = (n < N_NODES) ? deg[n] : 0;
    s[i] = v;
    __syncthreads();
    for (int st = 1; st < 256; st <<= 1) {
        int add = (i >= st) ? s[i - st] : 0;
        __syncthreads();
        s[i] += add;
        __syncthreads();
    }
    if (n < N_NODES) {
        int off = boff[blockIdx.x] + s[i] - v;
        offsets[n] = off;
        cursor[n] = off;
    }
    if (n == 0) offsets[N_NODES] = N_EDGES;
}

__global__ void k_place(const int* __restrict__ head, const int* __restrict__ tail,
                        const int* __restrict__ etype, int* __restrict__ cursor,
                        int* __restrict__ sorted) {
    int e = blockIdx.x * 256 + threadIdx.x;
    if (e >= N_EDGES) return;
    int h = head[e];
    int pos = atomicAdd(&cursor[h], 1);
    sorted[pos] = tail[e] | (etype[e] << 16);   // tail<65536, etype<32
}

// Hop 1: one wave per node; lane holds dims [4*lane, 4*lane+4). No atomics.
// 4-edge unroll for load ILP. Writes result already divided by deg.
__global__ void k_gather(const int* __restrict__ offsets, const int* __restrict__ sorted,
                         const float* __restrict__ relw, const float* __restrict__ src,
                         float* __restrict__ dst) {
    __shared__ __align__(16) f32x4 srel[2048];   // 32 rel x 256 dims = 32 KB
    int tid = threadIdx.x;
    for (int i = tid; i < 2048; i += 256) srel[i] = ((const f32x4*)relw)[i];
    __syncthreads();
    int w = tid >> 6, lane = tid & 63;
    int n = blockIdx.x * 4 + w;
    if (n >= N_NODES) return;
    int s = offsets[n], e = offsets[n + 1];
    f32x4 acc0 = (f32x4){0.f, 0.f, 0.f, 0.f};
    f32x4 acc1 = (f32x4){0.f, 0.f, 0.f, 0.f};
    f32x4 acc2 = (f32x4){0.f, 0.f, 0.f, 0.f};
    f32x4 acc3 = (f32x4){0.f, 0.f, 0.f, 0.f};
    int j = s;
    for (; j + 4 <= e; j += 4) {
        int p0 = sorted[j], p1 = sorted[j + 1], p2 = sorted[j + 2], p3 = sorted[j + 3];
        f32x4 v0 = *(const f32x4*)(src + (size_t)(p0 & 0xFFFF) * DIM + lane * 4);
        f32x4 v1 = *(const f32x4*)(src + (size_t)(p1 & 0xFFFF) * DIM + lane * 4);
        f32x4 v2 = *(const f32x4*)(src + (size_t)(p2 & 0xFFFF) * DIM + lane * 4);
        f32x4 v3 = *(const f32x4*)(src + (size_t)(p3 & 0xFFFF) * DIM + lane * 4);
        acc0 += v0 * srel[(p0 >> 16) * 64 + lane];
        acc1 += v1 * srel[(p1 >> 16) * 64 + lane];
        acc2 += v2 * srel[(p2 >> 16) * 64 + lane];
        acc3 += v3 * srel[(p3 >> 16) * 64 + lane];
    }
    for (; j < e; j++) {
        int p0 = sorted[j];
        f32x4 v0 = *(const f32x4*)(src + (size_t)(p0 & 0xFFFF) * DIM + lane * 4);
        acc0 += v0 * srel[(p0 >> 16) * 64 + lane];
    }
    acc0 = (acc0 + acc1) + (acc2 + acc3);
    float inv = 1.0f / fmaxf((float)(e - s), 1.0f);
    *(f32x4*)(dst + (size_t)n * DIM + lane * 4) = acc0 * inv;
}

// Hop 2 only at batch nodes, fused with struct = (emb + out1 + out2)/3.
__global__ void k_gather2(const int* __restrict__ nidx, const int* __restrict__ offsets,
                          const int* __restrict__ sorted, const float* __restrict__ relw,
                          const float* __restrict__ out1, const float* __restrict__ emb,
                          float* __restrict__ structb) {
    __shared__ __align__(16) f32x4 srel[2048];
    int tid = threadIdx.x;
    for (int i = tid; i < 2048; i += 256) srel[i] = ((const f32x4*)relw)[i];
    __syncthreads();
    int w = tid >> 6, lane = tid & 63;
    int b = blockIdx.x * 4 + w;          // grid = 1024 blocks, exact
    int n = nidx[b];
    int s = offsets[n], e = offsets[n + 1];
    f32x4 acc0 = (f32x4){0.f, 0.f, 0.f, 0.f};
    f32x4 acc1 = (f32x4){0.f, 0.f, 0.f, 0.f};
    f32x4 acc2 = (f32x4){0.f, 0.f, 0.f, 0.f};
    f32x4 acc3 = (f32x4){0.f, 0.f, 0.f, 0.f};
    int j = s;
    for (; j + 4 <= e; j += 4) {
        int p0 = sorted[j], p1 = sorted[j + 1], p2 = sorted[j + 2], p3 = sorted[j + 3];
        f32x4 v0 = *(const f32x4*)(out1 + (size_t)(p0 & 0xFFFF) * DIM + lane * 4);
        f32x4 v1 = *(const f32x4*)(out1 + (size_t)(p1 & 0xFFFF) * DIM + lane * 4);
        f32x4 v2 = *(const f32x4*)(out1 + (size_t)(p2 & 0xFFFF) * DIM + lane * 4);
        f32x4 v3 = *(const f32x4*)(out1 + (size_t)(p3 & 0xFFFF) * DIM + lane * 4);
        acc0 += v0 * srel[(p0 >> 16) * 64 + lane];
        acc1 += v1 * srel[(p1 >> 16) * 64 + lane];
        acc2 += v2 * srel[(p2 >> 16) * 64 + lane];
        acc3 += v3 * srel[(p3 >> 16) * 64 + lane];
    }
    for (; j < e; j++) {
        int p0 = sorted[j];
        f32x4 v0 = *(const f32x4*)(out1 + (size_t)(p0 & 0xFFFF) * DIM + lane * 4);
        acc0 += v0 * srel[(p0 >> 16) * 64 + lane];
    }
    acc0 = (acc0 + acc1) + (acc2 + acc3);
    float inv = 1.0f / fmaxf((float)(e - s), 1.0f);
    f32x4 o2 = acc0 * inv;
    f32x4 e0 = *(const f32x4*)(emb + (size_t)n * DIM + lane * 4);
    f32x4 o1 = *(const f32x4*)(out1 + (size_t)n * DIM + lane * 4);
    *(f32x4*)(structb + (size_t)b * DIM + lane * 4) = (e0 + o1 + o2) * (1.0f / 3.0f);
}

// ---------------- BiLSTM ----------------
// Pack W = [Wih | Whh] (bf16, K=192) into MFMA B-fragment order, 512-elem frags:
// per dir: frag = (w*4+g)*6+kc  (w=wave 0..7, g=gate 0..3, kc=0..5)
// within-frag = lane*8+j ; value = W[n][k],
//   n = g*128 + w*16 + (lane&15),  k = kc*32 + (lane>>4)*8 + j
__global__ void k_w2frag(const float* __restrict__ Wih_f, const float* __restrict__ Whh_f,
                         const float* __restrict__ Wih_b, const float* __restrict__ Whh_b,
                         __bf16* __restrict__ w2) {
    int idx = blockIdx.x * 256 + threadIdx.x;   // 2 * 192 * 512 = 196608
    int dir = idx / 98304;
    int rem = idx % 98304;
    int frag = rem >> 9;        // 0..191
    int within = rem & 511;
    int lane = within >> 3, j = within & 7;
    int kc = frag % 6;
    int wg = frag / 6;          // 0..31
    int g = wg & 3, w = wg >> 2;
    int n = g * 128 + w * 16 + (lane & 15);
    int k = kc * 32 + (lane >> 4) * 8 + j;
    const float* Wih = dir ? Wih_b : Wih_f;
    const float* Whh = dir ? Whh_b : Whh_f;
    float v = (k < 64) ? Wih[n * 64 + k] : Whh[n * 128 + (k - 64)];
    w2[idx] = (__bf16)v;
}

// Block = 8 waves (512 threads), 32 batch samples, one direction, all 50 steps.
// Wave w owns hidden cols j in [w*16, w*16+16) for ALL four gates.
// Weights live in VGPRs (24 x bf16x8 = 96 VGPRs/lane), loaded once before t-loop.
// x_{t+1} prefetched into registers so global latency hides behind MFMA+cell.
__launch_bounds__(512)
__global__ void k_lstm(const float* __restrict__ ts, const __bf16* __restrict__ w2frag,
                       const float* __restrict__ b_f, const float* __restrict__ b_b,
                       float* __restrict__ temporal) {
    int dir = blockIdx.y;
    int btile = blockIdx.x;    // 0..127
    int tid = threadIdx.x;
    int w = tid >> 6;          // wave 0..7
    int lane = tid & 63;
    int col = lane & 15, quad = lane >> 4;

    __shared__ __align__(16) __bf16 A[32][200];   // [m][k], K=192 padded to 200

    // zero h region (k = 64..191)
    for (int i = tid; i < 32 * 128; i += 512) {
        A[i >> 7][64 + (i & 127)] = (__bf16)0.0f;
    }

    const float* bias = dir ? b_b : b_f;
    float bv[4];
#pragma unroll
    for (int g = 0; g < 4; g++) {
        bv[g] = bias[g * 128 + w * 16 + col];
    }

    // weights -> registers, once
    const __bf16* wbase = w2frag + (size_t)dir * 98304 + (size_t)w * 12288;
    bf16x8 wreg[24];
#pragma unroll
    for (int f = 0; f < 24; f++) {
        wreg[f] = *(const bf16x8*)(wbase + (f << 9) + lane * 8);
    }

    // x staging: thread -> row sm = tid>>4, cols [sc4, sc4+4)
    int sm = tid >> 4, sc4 = (tid & 15) * 4;
    const float* xbase = ts + ((size_t)(btile * 32 + sm) * SEQ) * INP + sc4;
    f32x4 xpre = *(const f32x4*)(xbase + (size_t)(dir ? (SEQ - 1) : 0) * INP);

    f32x4 c_reg[2], hsum[2];
#pragma unroll
    for (int s = 0; s < 2; s++) {
        c_reg[s] = (f32x4){0.f, 0.f, 0.f, 0.f};
        hsum[s]  = (f32x4){0.f, 0.f, 0.f, 0.f};
    }
    __syncthreads();

    for (int t = 0; t < SEQ; t++) {
        // write prefetched x_t to LDS
        {
            bf16x4 xv;
            xv[0] = (__bf16)xpre.x; xv[1] = (__bf16)xpre.y;
            xv[2] = (__bf16)xpre.z; xv[3] = (__bf16)xpre.w;
            *(bf16x4*)&A[sm][sc4] = xv;
        }
        // prefetch x_{t+1} (consumed at next iteration's LDS write)
        if (t + 1 < SEQ) {
            int tt = dir ? (SEQ - 2 - t) : (t + 1);
            xpre = *(const f32x4*)(xbase + (size_t)tt * INP);
        }
        __syncthreads();

        f32x4 acc[8];
#pragma unroll
        for (int g = 0; g < 4; g++) {
            f32x4 z = (f32x4){bv[g], bv[g], bv[g], bv[g]};
            acc[g * 2] = z;
            acc[g * 2 + 1] = z;
        }
#pragma unroll
        for (int kc = 0; kc < 6; kc++) {
            bf16x8 a0 = *(const bf16x8*)&A[col][kc * 32 + quad * 8];
            bf16x8 a1 = *(const bf16x8*)&A[16 + col][kc * 32 + quad * 8];
#pragma unroll
            for (int g = 0; g < 4; g++) {
                bf16x8 bfrag = wreg[g * 6 + kc];
                acc[g * 2]     = __builtin_amdgcn_mfma_f32_16x16x32_bf16(a0, bfrag, acc[g * 2], 0, 0, 0);
                acc[g * 2 + 1] = __builtin_amdgcn_mfma_f32_16x16x32_bf16(a1, bfrag, acc[g * 2 + 1], 0, 0, 0);
            }
        }
        __syncthreads();   // everyone's A reads done before h_t overwrite

        // cell update: lane owns (b,j) pairs; i/f/g/o same lane, same reg idx
#pragma unroll
        for (int m = 0; m < 2; m++) {
#pragma unroll
            for (int r = 0; r < 4; r++) {
                float iv = acc[0 * 2 + m][r];
                float fv = acc[1 * 2 + m][r];
                float gv = acc[2 * 2 + m][r];
                float ov = acc[3 * 2 + m][r];
                float c = sigmoidf_(fv) * c_reg[m][r] + sigmoidf_(iv) * tanhf_(gv);
                float h = sigmoidf_(ov) * tanhf_(c);
                c_reg[m][r] = c;
                hsum[m][r] += h;
                A[m * 16 + quad * 4 + r][64 + w * 16 + col] = (__bf16)h;
            }
        }
    }

    // temporal[b][dir*128 + j] = mean over t of h
#pragma unroll
    for (int m = 0; m < 2; m++) {
#pragma unroll
        for (int r = 0; r < 4; r++) {
            int b = btile * 32 + m * 16 + quad * 4 + r;
            int j = w * 16 + col;
            temporal[(size_t)b * 256 + dir * 128 + j] = hsum[m][r] * (1.0f / SEQ);
        }
    }
}

// ---------------- Head ----------------

__global__ void k_gate(const float* __restrict__ structb, const float* __restrict__ temporal,
                       const float* __restrict__ gate_W, const float* __restrict__ gate_b,
                       float* __restrict__ merged) {
    int bt = blockIdx.x;      // 256 blocks x 16 samples
    int n = threadIdx.x;      // output unit
    __shared__ __align__(16) float cat[16][512];
    for (int i = n; i < 16 * 512; i += 256) {
        int bb = i >> 9, k = i & 511;
        int b = bt * 16 + bb;
        cat[bb][k] = (k < 256) ? structb[(size_t)b * 256 + k]
                               : temporal[(size_t)b * 256 + (k - 256)];
    }
    __syncthreads();
    float acc[16];
#pragma unroll
    for (int bb = 0; bb < 16; bb++) acc[bb] = gate_b[n];
    const float* wrow = gate_W + (size_t)n * 512;
    for (int k4 = 0; k4 < 512; k4 += 4) {
        f32x4 wv = *(const f32x4*)(wrow + k4);
#pragma unroll
        for (int bb = 0; bb < 16; bb++) {
            f32x4 cv = *(const f32x4*)&cat[bb][k4];
            acc[bb] += cv.x * wv.x + cv.y * wv.y + cv.z * wv.z + cv.w * wv.w;
        }
    }
    int b0 = bt * 16;
#pragma unroll
    for (int bb = 0; bb < 16; bb++) {
        float g = sigmoidf_(acc[bb]);
        float s = structb[(size_t)(b0 + bb) * 256 + n];
        float tm = temporal[(size_t)(b0 + bb) * 256 + n];
        merged[(size_t)(b0 + bb) * 256 + n] = g * s + (1.0f - g) * tm;
    }
}

__global__ void k_risk1(const float* __restrict__ merged, const float* __restrict__ W1,
                        const float* __restrict__ b1, float* __restrict__ t1) {
    int bt = blockIdx.x;      // 256 blocks x 16 samples
    int n = threadIdx.x;
    __shared__ __align__(16) float mt[16][256];
    for (int i = n; i < 16 * 256; i += 256) {
        int bb = i >> 8, k = i & 255;
        mt[bb][k] = merged[(size_t)(bt * 16 + bb) * 256 + k];
    }
    __syncthreads();
    float acc[16];
#pragma unroll
    for (int bb = 0; bb < 16; bb++) acc[bb] = b1[n];
    const float* wrow = W1 + (size_t)n * 256;
    for (int k4 = 0; k4 < 256; k4 += 4) {
        f32x4 wv = *(const f32x4*)(wrow + k4);
#pragma unroll
        for (int bb = 0; bb < 16; bb++) {
            f32x4 cv = *(const f32x4*)&mt[bb][k4];
            acc[bb] += cv.x * wv.x + cv.y * wv.y + cv.z * wv.z + cv.w * wv.w;
        }
    }
#pragma unroll
    for (int bb = 0; bb < 16; bb++) {
        t1[(size_t)(bt * 16 + bb) * 256 + n] = tanhf_(acc[bb]);
    }
}

// risk.sum(-1) collapses: sum_n(t1@W2^T + b2) = t1 . colsum(W2) + sum(b2)
__global__ void k_w2sum(const float* __restrict__ W2, const float* __restrict__ b2,
                        float* __restrict__ w2s) {
    int k = threadIdx.x;
    float s = 0.0f;
    for (int n = 0; n < 256; n++) s += W2[(size_t)n * 256 + k];
    w2s[k] = s;
    __shared__ float red[256];
    red[k] = b2[k];
    __syncthreads();
    for (int st = 128; st > 0; st >>= 1) {
        if (k < st) red[k] += red[k + st];
        __syncthreads();
    }
    if (k == 0) w2s[256] = red[0];
}

__global__ void k_final(const float* __restrict__ t1, const float* __restrict__ w2s,
                        float* __restrict__ out) {
    int b = (blockIdx.x * 256 + threadIdx.x) >> 6;   // one wave per sample
    int lane = threadIdx.x & 63;
    const float* row = t1 + (size_t)b * 256;
    float s = 0.0f;
#pragma unroll
    for (int q = 0; q < 4; q++) s += row[lane + q * 64] * w2s[lane + q * 64];
#pragma unroll
    for (int off = 32; off > 0; off >>= 1) s += __shfl_down(s, off, 64);
    if (lane == 0) out[b] = sigmoidf_(s + w2s[256]);
}

// ---------------- launch ----------------

extern "C" void kernel_launch(void* const* d_in, const int* in_sizes, int n_in,
                              void* d_out, int out_size, void* d_ws, size_t ws_size,
                              hipStream_t stream) {
    const float* ts       = (const float*)d_in[0];
    const float* node_emb = (const float*)d_in[1];
    const float* rel_w    = (const float*)d_in[2];
    const float* gate_W   = (const float*)d_in[3];
    const float* gate_b   = (const float*)d_in[4];
    const float* risk_W1  = (const float*)d_in[5];
    const float* risk_b1  = (const float*)d_in[6];
    const float* risk_W2  = (const float*)d_in[7];
    const float* risk_b2  = (const float*)d_in[8];
    const float* Wih_f    = (const float*)d_in[9];
    const float* Whh_f    = (const float*)d_in[10];
    const float* b_f      = (const float*)d_in[11];
    const float* Wih_b    = (const float*)d_in[12];
    const float* Whh_b    = (const float*)d_in[13];
    const float* b_b      = (const float*)d_in[14];
    const int* edge_index = (const int*)d_in[15];
    const int* edge_type  = (const int*)d_in[16];
    const int* node_idx   = (const int*)d_in[17];
    const int* head = edge_index;
    const int* tail = edge_index + N_EDGES;
    float* out = (float*)d_out;

    char* ws = (char*)d_ws;
    const size_t o_deg      = 0;                            // 50000 int
    const size_t o_deg_end  = 200704;
    const size_t o_bsum     = o_deg_end;                    // 196 int -> pad 1024
    const size_t o_boff     = o_bsum + 1024;                // 256 int
    const size_t o_offsets  = o_boff + 1024;                // 50001 int -> pad 200960
    const size_t o_cursor   = o_offsets + 200960;           // 50000 int
    const size_t o_sorted   = o_cursor + 200704;            // 300000 int
    const size_t o_out1     = o_sorted + 1200128;           // 51,200,000 B
    const size_t o_temporal = o_out1 + 51200000;            // 4 MB
    const size_t o_struct   = o_temporal + 4194304;
    const size_t o_merged   = o_struct + 4194304;
    const size_t o_t1       = o_merged + 4194304;
    const size_t o_w2s      = o_t1 + 4194304;
    const size_t o_w2frag   = o_w2s + 2048;                 // 393216 B

    int*    deg      = (int*)(ws + o_deg);
    int*    bsum     = (int*)(ws + o_bsum);
    int*    boff     = (int*)(ws + o_boff);
    int*    offsets  = (int*)(ws + o_offsets);
    int*    cursor   = (int*)(ws + o_cursor);
    int*    sorted   = (int*)(ws + o_sorted);
    float*  out1     = (float*)(ws + o_out1);
    float*  temporal = (float*)(ws + o_temporal);
    float*  structb  = (float*)(ws + o_struct);
    float*  merged   = (float*)(ws + o_merged);
    float*  t1       = (float*)(ws + o_t1);
    float*  w2s      = (float*)(ws + o_w2s);
    __bf16* w2frag   = (__bf16*)(ws + o_w2frag);

    hipMemsetAsync(deg, 0, N_NODES * sizeof(int), stream);

    k_w2frag<<<768, 256, 0, stream>>>(Wih_f, Whh_f, Wih_b, Whh_b, w2frag);
    k_hist<<<(N_EDGES + 255) / 256, 256, 0, stream>>>(head, deg);
    k_bsum<<<SCAN_BLOCKS, 256, 0, stream>>>(deg, bsum);
    k_scanb<<<1, 256, 0, stream>>>(bsum, boff);
    k_scan2<<<SCAN_BLOCKS, 256, 0, stream>>>(deg, boff, offsets, cursor);
    k_place<<<(N_EDGES + 255) / 256, 256, 0, stream>>>(head, tail, edge_type, cursor, sorted);
    k_gather<<<(N_NODES + 3) / 4, 256, 0, stream>>>(offsets, sorted, rel_w, node_emb, out1);
    k_lstm<<<dim3(BATCH / 32, 2), 512, 0, stream>>>(ts, w2frag, b_f, b_b, temporal);
    k_gather2<<<BATCH / 4, 256, 0, stream>>>(node_idx, offsets, sorted, rel_w, out1, node_emb, structb);
    k_gate<<<BATCH / 16, 256, 0, stream>>>(structb, temporal, gate_W, gate_b, merged);
    k_risk1<<<BATCH / 16, 256, 0, stream>>>(merged, risk_W1, risk_b1, t1);
    k_w2sum<<<1, 256, 0, stream>>>(risk_W2, risk_b2, w2s);
    k_final<<<BATCH / 4, 256, 0, stream>>>(t1, w2s, out);
}